// Round 1
// baseline (191.923 us; speedup 1.0000x reference)
//
#include <hip/hip_runtime.h>
#include <cstdint>

#define E_DIM   1024
#define DH      32
#define M_FEAT  256
#define BT      16384

// ---------------- Kernel 1: q/k projections -> z, lnA ----------------
// grid 256 x 512 threads; 64 tokens per block; 8 waves = 8 output groups of 8.
// og 0..3 -> q cols [8og, 8og+8); og 4..7 -> k cols [8(og-4), ...).
// Writes z[0..31] and lnA into out[token][0..32] (kernel 2 consumes then overwrites).
#define TBLK1 64
#define EC    128

__global__ __launch_bounds__(512, 2) void k_proj(
    const float* __restrict__ x, const float* __restrict__ Wq,
    const float* __restrict__ bq, const float* __restrict__ Wk,
    const float* __restrict__ bk, float* __restrict__ out)
{
    __shared__ float xlds[EC * 65];      // [e][tok], stride 65: conflict-free reads
    __shared__ float qk[TBLK1 * 65];     // [tok][out 0..63], stride 65

    const int tid = threadIdx.x;
    const int tok = tid & 63;
    const int og  = __builtin_amdgcn_readfirstlane(tid >> 6);   // wave-uniform 0..7
    const long t0 = (long)blockIdx.x * TBLK1;

    const float* __restrict__ W  = (og < 4) ? Wq : Wk;
    const float* __restrict__ bb = (og < 4) ? bq : bk;
    const int oc = (og & 3) * 8;

    float acc[8] = {0.f,0.f,0.f,0.f,0.f,0.f,0.f,0.f};

    // software pipeline: preload chunk 0 into registers
    float4 stage[4];
#pragma unroll
    for (int r = 0; r < 4; ++r) {
        int idx = r * 512 + tid;
        int tt = idx >> 5, e4 = idx & 31;
        stage[r] = *(const float4*)(x + (t0 + tt) * E_DIM + e4 * 4);
    }

    for (int e0 = 0; e0 < E_DIM; e0 += EC) {
        __syncthreads();   // previous chunk's compute done before overwrite
#pragma unroll
        for (int r = 0; r < 4; ++r) {
            int idx = r * 512 + tid;
            int tt = idx >> 5, e4 = idx & 31;
            int e = e4 * 4;
            xlds[(e + 0) * 65 + tt] = stage[r].x;
            xlds[(e + 1) * 65 + tt] = stage[r].y;
            xlds[(e + 2) * 65 + tt] = stage[r].z;
            xlds[(e + 3) * 65 + tt] = stage[r].w;
        }
        __syncthreads();
        // prefetch next chunk (overlaps with compute below)
        if (e0 + EC < E_DIM) {
#pragma unroll
            for (int r = 0; r < 4; ++r) {
                int idx = r * 512 + tid;
                int tt = idx >> 5, e4 = idx & 31;
                stage[r] = *(const float4*)(x + (t0 + tt) * E_DIM + (e0 + EC) + e4 * 4);
            }
        }
        // inner: 1 ds_read + 8 FMA per e; W reads are wave-uniform -> s_load
#pragma unroll 4
        for (int e = 0; e < EC; ++e) {
            float xe = xlds[e * 65 + tok];
            const float* wr = W + (size_t)(e0 + e) * DH + oc;
#pragma unroll
            for (int j = 0; j < 8; ++j)
                acc[j] = fmaf(xe, wr[j], acc[j]);
        }
    }

    // bias, stash into qk LDS
#pragma unroll
    for (int j = 0; j < 8; ++j) acc[j] += bb[oc + j];
#pragma unroll
    for (int j = 0; j < 8; ++j) qk[tok * 65 + og * 8 + j] = acc[j];
    __syncthreads();

    // per-token reduction: z = q + k, lnA = -0.5 * (|q|^2 + |k|^2)
    if (tid < 64) {
        const int t = tid;
        float z[32];
        float zs = 0.f;
#pragma unroll
        for (int d = 0; d < 32; ++d) {
            float qv = qk[t * 65 + d];
            float kv = qk[t * 65 + 32 + d];
            zs += qv * qv + kv * kv;
            z[d] = qv + kv;
        }
        float lnA = -0.5f * zs;
        float* orow = out + (t0 + t) * (size_t)M_FEAT;
#pragma unroll
        for (int d4 = 0; d4 < 8; ++d4)
            *(float4*)(orow + d4 * 4) =
                make_float4(z[d4*4+0], z[d4*4+1], z[d4*4+2], z[d4*4+3]);
        orow[32] = lnA;
    }
}

// ---------------- Kernel 2: R = exp(lnA) * cosh(z . w_m) ----------------
// grid 1024 x 256 threads; 16 tokens per block; thread = feature m.
// Reads z/lnA from out rows (written by k_proj), then overwrites full rows.
#define TBLK2 16

__global__ __launch_bounds__(256, 4) void k_feat(
    const float* __restrict__ w, float* __restrict__ out)
{
    const int m = threadIdx.x;
    const long t0 = (long)blockIdx.x * TBLK2;

    float wr[32];
#pragma unroll
    for (int d4 = 0; d4 < 8; ++d4) {
        float4 v = *(const float4*)(w + m * DH + d4 * 4);
        wr[d4*4+0] = v.x; wr[d4*4+1] = v.y; wr[d4*4+2] = v.z; wr[d4*4+3] = v.w;
    }

    float r[TBLK2];
#pragma unroll
    for (int tt = 0; tt < TBLK2; ++tt) {
        const float* zrow = out + (t0 + tt) * (size_t)M_FEAT;
        float zv[32];
#pragma unroll
        for (int d4 = 0; d4 < 8; ++d4) {
            float4 v = *(const float4*)(zrow + d4 * 4);
            zv[d4*4+0] = v.x; zv[d4*4+1] = v.y; zv[d4*4+2] = v.z; zv[d4*4+3] = v.w;
        }
        float lnA = zrow[32];
        float s = 0.f;
#pragma unroll
        for (int d = 0; d < 32; ++d) s = fmaf(zv[d], wr[d], s);
        // A*cosh(s) = 0.5*(exp(lnA+s) + exp(lnA-s)); overflow-safe
        r[tt] = 0.5f * (__expf(lnA + s) + __expf(lnA - s));
    }

    __syncthreads();   // all z reads (all threads) complete before any overwrite
#pragma unroll
    for (int tt = 0; tt < TBLK2; ++tt)
        out[(t0 + tt) * (size_t)M_FEAT + m] = r[tt];
}

extern "C" void kernel_launch(void* const* d_in, const int* in_sizes, int n_in,
                              void* d_out, int out_size, void* d_ws, size_t ws_size,
                              hipStream_t stream) {
    const float* x  = (const float*)d_in[0];
    const float* Wq = (const float*)d_in[1];
    const float* bq = (const float*)d_in[2];
    const float* Wk = (const float*)d_in[3];
    const float* bk = (const float*)d_in[4];
    // d_in[5], d_in[6] = Wv, bv: unused (v is dead in the reference)
    const float* w  = (const float*)d_in[7];
    float* out = (float*)d_out;

    k_proj<<<dim3(BT / TBLK1), dim3(512), 0, stream>>>(x, Wq, bq, Wk, bk, out);
    k_feat<<<dim3(BT / TBLK2), dim3(256), 0, stream>>>(w, out);
}

// Round 2
// 132.939 us; speedup vs baseline: 1.4437x; 1.4437x over previous
//
#include <hip/hip_runtime.h>
#include <cstdint>

#define E_DIM   1024
#define DH      32
#define M_FEAT  256
#define BT      16384

typedef __attribute__((ext_vector_type(8))) short bf16x8;
typedef __attribute__((ext_vector_type(4))) float f32x4;

// ws layout (shorts): wp_h[64][1024], wp_l[64][1024], wf_h[256][32], wf_l[256][32]
#define WP_H_OFF 0
#define WP_L_OFF (64*1024)
#define WF_H_OFF (2*64*1024)
#define WF_L_OFF (2*64*1024 + 256*32)

__device__ __forceinline__ void split_bf16(float f, short& h, short& l) {
    unsigned u = __builtin_bit_cast(unsigned, f);
    unsigned hr = (u + 0x7FFFu + ((u >> 16) & 1u)) & 0xFFFF0000u;  // RNE, as float bits
    h = (short)(hr >> 16);
    float fh = __builtin_bit_cast(float, hr);
    float d = f - fh;
    unsigned v = __builtin_bit_cast(unsigned, d);
    l = (short)((v + 0x7FFFu + ((v >> 16) & 1u)) >> 16);
}

__device__ __forceinline__ unsigned pack2(short a, short b) {
    return ((unsigned)(unsigned short)a) | (((unsigned)(unsigned short)b) << 16);
}

// ---------- prep: split Wcat=[Wq|Wk] -> wp (transposed [n][k]) and w -> wf ([n][k]) ----------
__global__ __launch_bounds__(256) void k_prep(
    const float* __restrict__ Wq, const float* __restrict__ Wk,
    const float* __restrict__ w, short* __restrict__ ws)
{
    int idx = blockIdx.x * 256 + threadIdx.x;
    short h[4], l[4];
    if (idx < 16384) {                       // proj: n 0..63, kq 0..255 (4 k each)
        int n = idx >> 8, kq = idx & 255;
        const float* src = (n < 32) ? (Wq + n) : (Wk + (n - 32));
#pragma unroll
        for (int j = 0; j < 4; ++j) split_bf16(src[(kq * 4 + j) * DH], h[j], l[j]);
        uint2 ph = make_uint2(pack2(h[0], h[1]), pack2(h[2], h[3]));
        uint2 pl = make_uint2(pack2(l[0], l[1]), pack2(l[2], l[3]));
        *(uint2*)(ws + WP_H_OFF + n * 1024 + kq * 4) = ph;
        *(uint2*)(ws + WP_L_OFF + n * 1024 + kq * 4) = pl;
    } else if (idx < 16384 + 2048) {         // feat: n 0..255, kq 0..7
        int j2 = idx - 16384;
        int n = j2 >> 3, kq = j2 & 7;
#pragma unroll
        for (int j = 0; j < 4; ++j) split_bf16(w[n * DH + kq * 4 + j], h[j], l[j]);
        uint2 ph = make_uint2(pack2(h[0], h[1]), pack2(h[2], h[3]));
        uint2 pl = make_uint2(pack2(l[0], l[1]), pack2(l[2], l[3]));
        *(uint2*)(ws + WF_H_OFF + n * DH + kq * 4) = ph;
        *(uint2*)(ws + WF_L_OFF + n * DH + kq * 4) = pl;
    }
}

// ---------- fused main: proj MFMA (3-pass split) -> z/lnA -> feature MFMA -> R ----------
// 512 blocks x 256 threads; 32 tokens/block. Wave wv owns proj n-tile [16wv,16wv+16).
#define XS 72   // x LDS row stride in shorts (64 data + 8 pad) = 144 B
#define QS 68   // qk row stride in floats = 272 B (16B-aligned, conflict-free quads)
#define ZS 40   // z row stride in shorts (32 data + 8 pad) = 80 B

__global__ __launch_bounds__(256) void k_main(
    const float* __restrict__ x, const float* __restrict__ bq,
    const float* __restrict__ bk, const short* __restrict__ ws,
    float* __restrict__ out)
{
    __shared__ __align__(16) short xh_s[32 * XS];
    __shared__ __align__(16) short xl_s[32 * XS];
    __shared__ __align__(16) float qk_f[32 * QS];
    __shared__ __align__(16) short zh_s[32 * ZS];
    __shared__ __align__(16) short zl_s[32 * ZS];
    __shared__ float lnA_f[32];

    const int tid  = threadIdx.x;
    const int lane = tid & 63;
    const int wv   = __builtin_amdgcn_readfirstlane(tid >> 6);  // 0..3
    const int ln15 = lane & 15;
    const int g    = lane >> 4;                                  // 0..3
    const long t0  = (long)blockIdx.x * 32;

    const short* wp_h = ws + WP_H_OFF;
    const short* wp_l = ws + WP_L_OFF;
    const short* wf_h = ws + WF_H_OFF;
    const short* wf_l = ws + WF_L_OFF;

    // -------- Phase 1: C[32 tok][64] = x @ [Wq|Wk]  (3-pass split bf16 MFMA) --------
    const int kq = tid & 15;          // k-quad 0..15 (64 k per chunk)
    const int mr = tid >> 4;          // row 0..15 (and mr+16)

    f32x4 acc0 = {0.f, 0.f, 0.f, 0.f};   // m-tile 0 (tok 0..15), n-tile wv
    f32x4 acc1 = {0.f, 0.f, 0.f, 0.f};   // m-tile 1 (tok 16..31)

    const int nrow = wv * 16 + ln15;     // proj output column 0..63

    float4 st0 = *(const float4*)(x + (t0 + mr) * E_DIM + kq * 4);
    float4 st1 = *(const float4*)(x + (t0 + mr + 16) * E_DIM + kq * 4);

    for (int c = 0; c < 16; ++c) {
        __syncthreads();   // prior chunk's LDS reads done
        {
            short h0,h1,h2,h3, l0,l1,l2,l3;
            split_bf16(st0.x,h0,l0); split_bf16(st0.y,h1,l1);
            split_bf16(st0.z,h2,l2); split_bf16(st0.w,h3,l3);
            *(uint2*)&xh_s[mr * XS + kq * 4] = make_uint2(pack2(h0,h1), pack2(h2,h3));
            *(uint2*)&xl_s[mr * XS + kq * 4] = make_uint2(pack2(l0,l1), pack2(l2,l3));
            split_bf16(st1.x,h0,l0); split_bf16(st1.y,h1,l1);
            split_bf16(st1.z,h2,l2); split_bf16(st1.w,h3,l3);
            *(uint2*)&xh_s[(mr+16) * XS + kq * 4] = make_uint2(pack2(h0,h1), pack2(h2,h3));
            *(uint2*)&xl_s[(mr+16) * XS + kq * 4] = make_uint2(pack2(l0,l1), pack2(l2,l3));
        }
        __syncthreads();
        if (c < 15) {   // prefetch next chunk while computing this one
            st0 = *(const float4*)(x + (t0 + mr) * E_DIM + (c+1)*64 + kq * 4);
            st1 = *(const float4*)(x + (t0 + mr + 16) * E_DIM + (c+1)*64 + kq * 4);
        }
#pragma unroll
        for (int s = 0; s < 2; ++s) {
            const int kb = c * 64 + s * 32;
            bf16x8 bh = *(const bf16x8*)(wp_h + nrow * 1024 + kb + g * 8);
            bf16x8 bl = *(const bf16x8*)(wp_l + nrow * 1024 + kb + g * 8);
            bf16x8 a0h = *(const bf16x8*)&xh_s[ln15 * XS + s * 32 + g * 8];
            bf16x8 a0l = *(const bf16x8*)&xl_s[ln15 * XS + s * 32 + g * 8];
            bf16x8 a1h = *(const bf16x8*)&xh_s[(ln15 + 16) * XS + s * 32 + g * 8];
            bf16x8 a1l = *(const bf16x8*)&xl_s[(ln15 + 16) * XS + s * 32 + g * 8];
            acc0 = __builtin_amdgcn_mfma_f32_16x16x32_bf16(a0h, bh, acc0, 0, 0, 0);
            acc0 = __builtin_amdgcn_mfma_f32_16x16x32_bf16(a0h, bl, acc0, 0, 0, 0);
            acc0 = __builtin_amdgcn_mfma_f32_16x16x32_bf16(a0l, bh, acc0, 0, 0, 0);
            acc1 = __builtin_amdgcn_mfma_f32_16x16x32_bf16(a1h, bh, acc1, 0, 0, 0);
            acc1 = __builtin_amdgcn_mfma_f32_16x16x32_bf16(a1h, bl, acc1, 0, 0, 0);
            acc1 = __builtin_amdgcn_mfma_f32_16x16x32_bf16(a1l, bh, acc1, 0, 0, 0);
        }
    }

    // -------- Phase 2: +bias, C -> qk LDS (C-layout: col=lane&15, row=g*4+reg) --------
    {
        const float bias = (nrow < 32) ? bq[nrow] : bk[nrow - 32];
#pragma unroll
        for (int r = 0; r < 4; ++r) {
            qk_f[(g * 4 + r) * QS + nrow]      = acc0[r] + bias;
            qk_f[(16 + g * 4 + r) * QS + nrow] = acc1[r] + bias;
        }
    }
    __syncthreads();

    // -------- Phase 3: z = q+k (bf16 split), lnA = -0.5(|q|^2+|k|^2) --------
    {
        const int tok = tid >> 3, grp = tid & 7;
        float4 qv = *(const float4*)&qk_f[tok * QS + grp * 4];
        float4 kv = *(const float4*)&qk_f[tok * QS + 32 + grp * 4];
        float z0 = qv.x + kv.x, z1 = qv.y + kv.y, z2 = qv.z + kv.z, z3 = qv.w + kv.w;
        float p = qv.x*qv.x + qv.y*qv.y + qv.z*qv.z + qv.w*qv.w
                + kv.x*kv.x + kv.y*kv.y + kv.z*kv.z + kv.w*kv.w;
        short h0,h1,h2,h3, l0,l1,l2,l3;
        split_bf16(z0,h0,l0); split_bf16(z1,h1,l1);
        split_bf16(z2,h2,l2); split_bf16(z3,h3,l3);
        *(uint2*)&zh_s[tok * ZS + grp * 4] = make_uint2(pack2(h0,h1), pack2(h2,h3));
        *(uint2*)&zl_s[tok * ZS + grp * 4] = make_uint2(pack2(l0,l1), pack2(l2,l3));
        p += __shfl_xor(p, 1);
        p += __shfl_xor(p, 2);
        p += __shfl_xor(p, 4);
        if (grp == 0) lnA_f[tok] = -0.5f * p;
    }
    __syncthreads();

    // -------- Phase 4: S[32 tok][256] = z @ w^T (3-pass split), wave wv owns n-tiles wv*4.. --------
    f32x4 facc[4][2];
#pragma unroll
    for (int i = 0; i < 4; ++i)
#pragma unroll
        for (int mt = 0; mt < 2; ++mt) facc[i][mt] = (f32x4){0.f,0.f,0.f,0.f};

    bf16x8 a_h[2], a_l[2];
#pragma unroll
    for (int mt = 0; mt < 2; ++mt) {
        a_h[mt] = *(const bf16x8*)&zh_s[(mt * 16 + ln15) * ZS + g * 8];
        a_l[mt] = *(const bf16x8*)&zl_s[(mt * 16 + ln15) * ZS + g * 8];
    }
#pragma unroll
    for (int i = 0; i < 4; ++i) {
        const int nf = (wv * 4 + i) * 16 + ln15;     // feature index 0..255
        bf16x8 bh = *(const bf16x8*)(wf_h + nf * DH + g * 8);
        bf16x8 bl = *(const bf16x8*)(wf_l + nf * DH + g * 8);
#pragma unroll
        for (int mt = 0; mt < 2; ++mt) {
            facc[i][mt] = __builtin_amdgcn_mfma_f32_16x16x32_bf16(a_h[mt], bh, facc[i][mt], 0, 0, 0);
            facc[i][mt] = __builtin_amdgcn_mfma_f32_16x16x32_bf16(a_h[mt], bl, facc[i][mt], 0, 0, 0);
            facc[i][mt] = __builtin_amdgcn_mfma_f32_16x16x32_bf16(a_l[mt], bh, facc[i][mt], 0, 0, 0);
        }
    }

    // -------- Phase 5: R = 0.5*(exp(lnA+s)+exp(lnA-s)), direct stores --------
    float lnAv[2][4];
#pragma unroll
    for (int mt = 0; mt < 2; ++mt)
#pragma unroll
        for (int r = 0; r < 4; ++r) lnAv[mt][r] = lnA_f[mt * 16 + g * 4 + r];

#pragma unroll
    for (int i = 0; i < 4; ++i) {
        const int n = (wv * 4 + i) * 16 + ln15;
#pragma unroll
        for (int mt = 0; mt < 2; ++mt) {
#pragma unroll
            for (int r = 0; r < 4; ++r) {
                float s = facc[i][mt][r];
                float R = 0.5f * (__expf(lnAv[mt][r] + s) + __expf(lnAv[mt][r] - s));
                out[(t0 + mt * 16 + g * 4 + r) * M_FEAT + n] = R;
            }
        }
    }
}

extern "C" void kernel_launch(void* const* d_in, const int* in_sizes, int n_in,
                              void* d_out, int out_size, void* d_ws, size_t ws_size,
                              hipStream_t stream) {
    const float* x  = (const float*)d_in[0];
    const float* Wq = (const float*)d_in[1];
    const float* bq = (const float*)d_in[2];
    const float* Wk = (const float*)d_in[3];
    const float* bk = (const float*)d_in[4];
    // d_in[5], d_in[6] = Wv, bv: dead in the reference
    const float* w  = (const float*)d_in[7];
    float* out = (float*)d_out;
    short* ws  = (short*)d_ws;   // needs 288 KB

    k_prep<<<dim3(72), dim3(256), 0, stream>>>(Wq, Wk, w, ws);
    k_main<<<dim3(BT / 32), dim3(256), 0, stream>>>(x, bq, bk, ws, out);
}

// Round 3
// 127.536 us; speedup vs baseline: 1.5049x; 1.0424x over previous
//
#include <hip/hip_runtime.h>
#include <cstdint>

#define E_DIM   1024
#define DH      32
#define M_FEAT  256
#define BT      16384

typedef __attribute__((ext_vector_type(8))) short bf16x8;
typedef __attribute__((ext_vector_type(4))) float f32x4;

// ws layout (shorts):
//  wp_h / wp_l : proj W in MFMA-fragment order [(nt*16+c)*2+s][lane0..63][8]  (64K shorts each)
//  wf_h / wf_l : feature w as [n=256][k=32]                                   (8K shorts each)
#define WP_H_OFF 0
#define WP_L_OFF 65536
#define WF_H_OFF 131072
#define WF_L_OFF (131072 + 8192)

__device__ __forceinline__ void split_bf16(float f, short& h, short& l) {
    unsigned u = __builtin_bit_cast(unsigned, f);
    unsigned hr = (u + 0x7FFFu + ((u >> 16) & 1u)) & 0xFFFF0000u;  // RNE high half
    h = (short)(hr >> 16);
    float fh = __builtin_bit_cast(float, hr);
    float d = f - fh;
    unsigned v = __builtin_bit_cast(unsigned, d);
    l = (short)((v + 0x7FFFu + ((v >> 16) & 1u)) >> 16);
}

__device__ __forceinline__ unsigned pack2(short a, short b) {
    return ((unsigned)(unsigned short)a) | (((unsigned)(unsigned short)b) << 16);
}

// ---------- prep: coalesced LDS-transpose split of [Wq|Wk] into fragment order; w -> wf ----------
__global__ __launch_bounds__(256) void k_prep(
    const float* __restrict__ Wq, const float* __restrict__ Wk,
    const float* __restrict__ w, short* __restrict__ ws)
{
    __shared__ float wlds[128 * 36];   // [k 0..127][n 0..31], stride 36 floats
    const int b = blockIdx.x, tid = threadIdx.x;
    if (b < 16) {
        const float* __restrict__ src = (b < 8) ? Wq : Wk;
        const int k0 = (b & 7) * 128;
        const int nbase = (b < 8) ? 0 : 32;
#pragma unroll
        for (int it = 0; it < 4; ++it) {               // coalesced read 128x32 floats
            int f = it * 256 + tid;                    // float4 index
            int k = f >> 3, c4 = f & 7;
            float4 v = *(const float4*)(src + (size_t)(k0 + k) * DH + c4 * 4);
            *(float4*)&wlds[k * 36 + c4 * 4] = v;
        }
        __syncthreads();
        const int n = tid >> 3, kq = tid & 7;
        const int n_g = nbase + n;
        const int nt = n_g >> 4, ln = n_g & 15;
#pragma unroll
        for (int rep = 0; rep < 4; ++rep) {
            int kk = rep * 8 + kq;                     // 0..31 -> k quad within this 128-slab
            int k_g = k0 + kk * 4;
            short h[4], l[4];
#pragma unroll
            for (int j = 0; j < 4; ++j)
                split_bf16(wlds[(kk * 4 + j) * 36 + n], h[j], l[j]);
            int c = k_g >> 6, s = (k_g >> 5) & 1, g = (k_g >> 3) & 3, j0 = k_g & 7;
            int lane = g * 16 + ln;
            size_t flat = ((size_t)((nt * 16 + c) * 2 + s)) * 512 + lane * 8 + j0;
            *(uint2*)(ws + WP_H_OFF + flat) = make_uint2(pack2(h[0],h[1]), pack2(h[2],h[3]));
            *(uint2*)(ws + WP_L_OFF + flat) = make_uint2(pack2(l[0],l[1]), pack2(l[2],l[3]));
        }
    } else {
        // w is [256][32] row-major == [n][k]: layout already fragment-friendly
#pragma unroll
        for (int it = 0; it < 8; ++it) {
            int f = it * 256 + tid;                    // float4 index 0..2047
            float4 v = *(const float4*)(w + (size_t)f * 4);
            short h[4], l[4];
            split_bf16(v.x,h[0],l[0]); split_bf16(v.y,h[1],l[1]);
            split_bf16(v.z,h[2],l[2]); split_bf16(v.w,h[3],l[3]);
            *(uint2*)(ws + WF_H_OFF + f * 4) = make_uint2(pack2(h[0],h[1]), pack2(h[2],h[3]));
            *(uint2*)(ws + WF_L_OFF + f * 4) = make_uint2(pack2(l[0],l[1]), pack2(l[2],l[3]));
        }
    }
}

// ---------- fused main: 16 tokens/block, grid 1024 (4 blocks/CU), dbuf LDS, 1 barrier/chunk ----------
#define TB 16
#define XS 72   // x LDS row stride in shorts (64 data + 8 pad) = 144 B, b128-aligned
#define QS 68   // qk row stride in floats
#define ZS 40   // z row stride in shorts

__global__ __launch_bounds__(256) void k_main(
    const float* __restrict__ x, const float* __restrict__ bq,
    const float* __restrict__ bk, const short* __restrict__ ws,
    float* __restrict__ out)
{
    __shared__ __align__(16) short xh_s[2][TB * XS];
    __shared__ __align__(16) short xl_s[2][TB * XS];
    __shared__ __align__(16) float qk_f[TB * QS];
    __shared__ __align__(16) short zh_s[TB * ZS];
    __shared__ __align__(16) short zl_s[TB * ZS];
    __shared__ float lnA_f[TB];

    const int tid  = threadIdx.x;
    const int lane = tid & 63;
    const int wv   = __builtin_amdgcn_readfirstlane(tid >> 6);  // 0..3
    const int ln15 = lane & 15;
    const int g    = lane >> 4;                                  // 0..3
    const long t0  = (long)blockIdx.x * TB;

    // -------- Phase 1: C[16 tok][64] = x @ [Wq|Wk] (3-pass split bf16 MFMA) --------
    const int kq = tid & 15;          // k-quad 0..15 within 64-wide chunk
    const int mr = tid >> 4;          // token row 0..15

    f32x4 acc = {0.f, 0.f, 0.f, 0.f};

    float4 st = *(const float4*)(x + (t0 + mr) * E_DIM + kq * 4);
    {   // stage chunk 0 -> buf 0
        short h0,h1,h2,h3, l0,l1,l2,l3;
        split_bf16(st.x,h0,l0); split_bf16(st.y,h1,l1);
        split_bf16(st.z,h2,l2); split_bf16(st.w,h3,l3);
        *(uint2*)&xh_s[0][mr * XS + kq * 4] = make_uint2(pack2(h0,h1), pack2(h2,h3));
        *(uint2*)&xl_s[0][mr * XS + kq * 4] = make_uint2(pack2(l0,l1), pack2(l2,l3));
    }

    for (int c = 0; c < 16; ++c) {
        __syncthreads();              // buf (c&1) fully written; prior reads of other buf done
        if (c < 15)                   // prefetch next chunk (lands during MFMA below)
            st = *(const float4*)(x + (t0 + mr) * E_DIM + (c + 1) * 64 + kq * 4);
#pragma unroll
        for (int s = 0; s < 2; ++s) {
            size_t fb = ((size_t)((wv * 16 + c) * 2 + s)) * 512 + lane * 8;
            bf16x8 bh = *(const bf16x8*)(ws + WP_H_OFF + fb);   // contiguous 1KB/wave
            bf16x8 bl = *(const bf16x8*)(ws + WP_L_OFF + fb);
            bf16x8 ah = *(const bf16x8*)&xh_s[c & 1][ln15 * XS + s * 32 + g * 8];
            bf16x8 al = *(const bf16x8*)&xl_s[c & 1][ln15 * XS + s * 32 + g * 8];
            acc = __builtin_amdgcn_mfma_f32_16x16x32_bf16(ah, bh, acc, 0, 0, 0);
            acc = __builtin_amdgcn_mfma_f32_16x16x32_bf16(ah, bl, acc, 0, 0, 0);
            acc = __builtin_amdgcn_mfma_f32_16x16x32_bf16(al, bh, acc, 0, 0, 0);
        }
        if (c < 15) {                 // write staged chunk c+1 into the other buffer
            short h0,h1,h2,h3, l0,l1,l2,l3;
            split_bf16(st.x,h0,l0); split_bf16(st.y,h1,l1);
            split_bf16(st.z,h2,l2); split_bf16(st.w,h3,l3);
            *(uint2*)&xh_s[(c + 1) & 1][mr * XS + kq * 4] = make_uint2(pack2(h0,h1), pack2(h2,h3));
            *(uint2*)&xl_s[(c + 1) & 1][mr * XS + kq * 4] = make_uint2(pack2(l0,l1), pack2(l2,l3));
        }
    }

    // -------- Phase 2: +bias -> qk LDS (C-layout: col(tok)=ln15? no: row=tok) --------
    // C/D layout: token = g*4+r (row), output col = ln15 -> nrow below
    const int nrow = wv * 16 + ln15;  // proj output column 0..63
    {
        const float bias = (nrow < 32) ? bq[nrow] : bk[nrow - 32];
#pragma unroll
        for (int r = 0; r < 4; ++r)
            qk_f[(g * 4 + r) * QS + nrow] = acc[r] + bias;
    }
    __syncthreads();

    // -------- Phase 3: z = q+k (split), lnA = -0.5(|q|^2+|k|^2) --------
    if (tid < 128) {
        const int tok = tid >> 3, grp = tid & 7;
        float4 qv = *(const float4*)&qk_f[tok * QS + grp * 4];
        float4 kv = *(const float4*)&qk_f[tok * QS + 32 + grp * 4];
        float z0 = qv.x + kv.x, z1 = qv.y + kv.y, z2 = qv.z + kv.z, z3 = qv.w + kv.w;
        float p = qv.x*qv.x + qv.y*qv.y + qv.z*qv.z + qv.w*qv.w
                + kv.x*kv.x + kv.y*kv.y + kv.z*kv.z + kv.w*kv.w;
        short h0,h1,h2,h3, l0,l1,l2,l3;
        split_bf16(z0,h0,l0); split_bf16(z1,h1,l1);
        split_bf16(z2,h2,l2); split_bf16(z3,h3,l3);
        *(uint2*)&zh_s[tok * ZS + grp * 4] = make_uint2(pack2(h0,h1), pack2(h2,h3));
        *(uint2*)&zl_s[tok * ZS + grp * 4] = make_uint2(pack2(l0,l1), pack2(l2,l3));
        p += __shfl_xor(p, 1);
        p += __shfl_xor(p, 2);
        p += __shfl_xor(p, 4);
        if (grp == 0) lnA_f[tok] = -0.5f * p;
    }
    __syncthreads();

    // -------- Phase 4: S[16 tok][256] = z @ w^T (3-pass split); wave wv: features wv*64.. --------
    f32x4 facc[4];
#pragma unroll
    for (int i = 0; i < 4; ++i) facc[i] = (f32x4){0.f,0.f,0.f,0.f};

    bf16x8 a_h = *(const bf16x8*)&zh_s[ln15 * ZS + g * 8];
    bf16x8 a_l = *(const bf16x8*)&zl_s[ln15 * ZS + g * 8];
#pragma unroll
    for (int i = 0; i < 4; ++i) {
        const int nf = (wv * 4 + i) * 16 + ln15;    // feature 0..255
        bf16x8 bh = *(const bf16x8*)(ws + WF_H_OFF + (size_t)nf * DH + g * 8);
        bf16x8 bl = *(const bf16x8*)(ws + WF_L_OFF + (size_t)nf * DH + g * 8);
        facc[i] = __builtin_amdgcn_mfma_f32_16x16x32_bf16(a_h, bh, facc[i], 0, 0, 0);
        facc[i] = __builtin_amdgcn_mfma_f32_16x16x32_bf16(a_h, bl, facc[i], 0, 0, 0);
        facc[i] = __builtin_amdgcn_mfma_f32_16x16x32_bf16(a_l, bh, facc[i], 0, 0, 0);
    }

    // -------- Phase 5: R = 0.5*(exp(lnA+s)+exp(lnA-s)) --------
    float lnAv[4];
#pragma unroll
    for (int r = 0; r < 4; ++r) lnAv[r] = lnA_f[g * 4 + r];

#pragma unroll
    for (int i = 0; i < 4; ++i) {
        const int n = (wv * 4 + i) * 16 + ln15;
#pragma unroll
        for (int r = 0; r < 4; ++r) {
            float s = facc[i][r];
            float R = 0.5f * (__expf(lnAv[r] + s) + __expf(lnAv[r] - s));
            out[(t0 + g * 4 + r) * M_FEAT + n] = R;
        }
    }
}

extern "C" void kernel_launch(void* const* d_in, const int* in_sizes, int n_in,
                              void* d_out, int out_size, void* d_ws, size_t ws_size,
                              hipStream_t stream) {
    const float* x  = (const float*)d_in[0];
    const float* Wq = (const float*)d_in[1];
    const float* bq = (const float*)d_in[2];
    const float* Wk = (const float*)d_in[3];
    const float* bk = (const float*)d_in[4];
    // d_in[5], d_in[6] = Wv, bv: dead in the reference
    const float* w  = (const float*)d_in[7];
    float* out = (float*)d_out;
    short* ws  = (short*)d_ws;   // 288 KB used

    k_prep<<<dim3(17), dim3(256), 0, stream>>>(Wq, Wk, w, ws);
    k_main<<<dim3(BT / TB), dim3(256), 0, stream>>>(x, bq, bk, ws, out);
}

// Round 4
// 124.108 us; speedup vs baseline: 1.5464x; 1.0276x over previous
//
#include <hip/hip_runtime.h>
#include <cstdint>

#define E_DIM   1024
#define DH      32
#define M_FEAT  256
#define BT      16384

typedef __attribute__((ext_vector_type(8))) short bf16x8;
typedef __attribute__((ext_vector_type(4))) float f32x4;

// ws layout (shorts):
//  wp_h / wp_l : proj W in MFMA-fragment order, flat = (nt*32 + sub)*512 + lane*8
//                (sub = global 32-k subchunk 0..31)                        (64K shorts each)
//  wf_h / wf_l : feature w as [n=256][k=32]                                (8K shorts each)
#define WP_H_OFF 0
#define WP_L_OFF 65536
#define WF_H_OFF 131072
#define WF_L_OFF (131072 + 8192)

__device__ __forceinline__ void split_bf16(float f, short& h, short& l) {
    unsigned u = __builtin_bit_cast(unsigned, f);
    unsigned hr = (u + 0x7FFFu + ((u >> 16) & 1u)) & 0xFFFF0000u;  // RNE high half
    h = (short)(hr >> 16);
    float fh = __builtin_bit_cast(float, hr);
    float d = f - fh;
    unsigned v = __builtin_bit_cast(unsigned, d);
    l = (short)((v + 0x7FFFu + ((v >> 16) & 1u)) >> 16);
}

__device__ __forceinline__ unsigned pack2(short a, short b) {
    return ((unsigned)(unsigned short)a) | (((unsigned)(unsigned short)b) << 16);
}

// ---------- prep: coalesced LDS-transpose split of [Wq|Wk] into fragment order; w -> wf ----------
__global__ __launch_bounds__(256) void k_prep(
    const float* __restrict__ Wq, const float* __restrict__ Wk,
    const float* __restrict__ w, short* __restrict__ ws)
{
    __shared__ float wlds[128 * 36];   // [k 0..127][n 0..31], stride 36 floats
    const int b = blockIdx.x, tid = threadIdx.x;
    if (b < 16) {
        const float* __restrict__ src = (b < 8) ? Wq : Wk;
        const int k0 = (b & 7) * 128;
        const int nbase = (b < 8) ? 0 : 32;
#pragma unroll
        for (int it = 0; it < 4; ++it) {               // coalesced read 128x32 floats
            int f = it * 256 + tid;                    // float4 index
            int k = f >> 3, c4 = f & 7;
            float4 v = *(const float4*)(src + (size_t)(k0 + k) * DH + c4 * 4);
            *(float4*)&wlds[k * 36 + c4 * 4] = v;
        }
        __syncthreads();
        const int n = tid >> 3, kq = tid & 7;
        const int n_g = nbase + n;
        const int nt = n_g >> 4, ln = n_g & 15;
#pragma unroll
        for (int rep = 0; rep < 4; ++rep) {
            int kk = rep * 8 + kq;                     // k-quad within this 128-slab
            int k_g = k0 + kk * 4;
            short h[4], l[4];
#pragma unroll
            for (int j = 0; j < 4; ++j)
                split_bf16(wlds[(kk * 4 + j) * 36 + n], h[j], l[j]);
            int sub = k_g >> 5;                        // global 32-k subchunk 0..31
            int g = (k_g >> 3) & 3, j0 = k_g & 7;
            int lane = g * 16 + ln;
            size_t flat = ((size_t)(nt * 32 + sub)) * 512 + lane * 8 + j0;
            *(uint2*)(ws + WP_H_OFF + flat) = make_uint2(pack2(h[0],h[1]), pack2(h[2],h[3]));
            *(uint2*)(ws + WP_L_OFF + flat) = make_uint2(pack2(l[0],l[1]), pack2(l[2],l[3]));
        }
    } else {
        // w is [256][32] row-major == [n][k]: already fragment-friendly
#pragma unroll
        for (int it = 0; it < 8; ++it) {
            int f = it * 256 + tid;                    // float4 index 0..2047
            float4 v = *(const float4*)(w + (size_t)f * 4);
            short h[4], l[4];
            split_bf16(v.x,h[0],l[0]); split_bf16(v.y,h[1],l[1]);
            split_bf16(v.z,h[2],l[2]); split_bf16(v.w,h[3],l[3]);
            *(uint2*)(ws + WF_H_OFF + f * 4) = make_uint2(pack2(h[0],h[1]), pack2(h[2],h[3]));
            *(uint2*)(ws + WF_L_OFF + f * 4) = make_uint2(pack2(l[0],l[1]), pack2(l[2],l[3]));
        }
    }
}

// ---------- fused main: 16 tok/block, BK=128 pairs, dbuf LDS + dbuf B-frag registers ----------
#define TB 16
#define XS2 136  // x LDS row stride in shorts (128 data + 8 pad) = 272 B
#define QS 68    // qk row stride in floats
#define ZS 40    // z row stride in shorts

__global__ __launch_bounds__(256, 4) void k_main(
    const float* __restrict__ x, const float* __restrict__ bq,
    const float* __restrict__ bk, const short* __restrict__ ws,
    float* __restrict__ out)
{
    __shared__ __align__(16) short xh_s[2][TB * XS2];
    __shared__ __align__(16) short xl_s[2][TB * XS2];
    __shared__ __align__(16) float qk_f[TB * QS];
    __shared__ __align__(16) short zh_s[TB * ZS];
    __shared__ __align__(16) short zl_s[TB * ZS];
    __shared__ float lnA_f[TB];

    const int tid  = threadIdx.x;
    const int lane = tid & 63;
    const int wv   = __builtin_amdgcn_readfirstlane(tid >> 6);  // 0..3
    const int ln15 = lane & 15;
    const int g    = lane >> 4;                                  // 0..3
    const long t0  = (long)blockIdx.x * TB;

    // -------- Phase 1: C[16 tok][64] = x @ [Wq|Wk] (3-pass split bf16 MFMA) --------
    const int kq = tid & 15;          // 8-k group 0..15 within 128-wide pair
    const int mr = tid >> 4;          // token row 0..15

    f32x4 acc = {0.f, 0.f, 0.f, 0.f};

    const short* wpB_h = ws + WP_H_OFF + (size_t)(wv * 32) * 512 + lane * 8;
    const short* wpB_l = ws + WP_L_OFF + (size_t)(wv * 32) * 512 + lane * 8;
    const float* xrow  = x + (t0 + mr) * E_DIM + kq * 8;

    // stage pair 0 + preload its B fragments
    float4 sa = *(const float4*)(xrow + 0);
    float4 sb = *(const float4*)(xrow + 4);
    bf16x8 bcur_h[4], bcur_l[4], bnxt_h[4], bnxt_l[4];
#pragma unroll
    for (int j = 0; j < 4; ++j) {
        bcur_h[j] = *(const bf16x8*)(wpB_h + (size_t)j * 512);
        bcur_l[j] = *(const bf16x8*)(wpB_l + (size_t)j * 512);
    }
    {
        short h[8], l[8];
        split_bf16(sa.x,h[0],l[0]); split_bf16(sa.y,h[1],l[1]);
        split_bf16(sa.z,h[2],l[2]); split_bf16(sa.w,h[3],l[3]);
        split_bf16(sb.x,h[4],l[4]); split_bf16(sb.y,h[5],l[5]);
        split_bf16(sb.z,h[6],l[6]); split_bf16(sb.w,h[7],l[7]);
        uint4 uh = make_uint4(pack2(h[0],h[1]),pack2(h[2],h[3]),pack2(h[4],h[5]),pack2(h[6],h[7]));
        uint4 ul = make_uint4(pack2(l[0],l[1]),pack2(l[2],l[3]),pack2(l[4],l[5]),pack2(l[6],l[7]));
        *(uint4*)&xh_s[0][mr * XS2 + kq * 8] = uh;
        *(uint4*)&xl_s[0][mr * XS2 + kq * 8] = ul;
    }

#pragma unroll
    for (int p = 0; p < 8; ++p) {
        __syncthreads();              // buf (p&1) fully staged; prior reads of it done
        if (p < 7) {                  // prefetch next pair: x + B frags (full pair-period window)
            sa = *(const float4*)(xrow + (p + 1) * 128);
            sb = *(const float4*)(xrow + (p + 1) * 128 + 4);
#pragma unroll
            for (int j = 0; j < 4; ++j) {
                bnxt_h[j] = *(const bf16x8*)(wpB_h + (size_t)((p + 1) * 4 + j) * 512);
                bnxt_l[j] = *(const bf16x8*)(wpB_l + (size_t)((p + 1) * 4 + j) * 512);
            }
        }
#pragma unroll
        for (int j = 0; j < 4; ++j) {
            bf16x8 ah = *(const bf16x8*)&xh_s[p & 1][ln15 * XS2 + j * 32 + g * 8];
            bf16x8 al = *(const bf16x8*)&xl_s[p & 1][ln15 * XS2 + j * 32 + g * 8];
            acc = __builtin_amdgcn_mfma_f32_16x16x32_bf16(ah, bcur_h[j], acc, 0, 0, 0);
            acc = __builtin_amdgcn_mfma_f32_16x16x32_bf16(ah, bcur_l[j], acc, 0, 0, 0);
            acc = __builtin_amdgcn_mfma_f32_16x16x32_bf16(al, bcur_h[j], acc, 0, 0, 0);
        }
        if (p < 7) {
            short h[8], l[8];
            split_bf16(sa.x,h[0],l[0]); split_bf16(sa.y,h[1],l[1]);
            split_bf16(sa.z,h[2],l[2]); split_bf16(sa.w,h[3],l[3]);
            split_bf16(sb.x,h[4],l[4]); split_bf16(sb.y,h[5],l[5]);
            split_bf16(sb.z,h[6],l[6]); split_bf16(sb.w,h[7],l[7]);
            uint4 uh = make_uint4(pack2(h[0],h[1]),pack2(h[2],h[3]),pack2(h[4],h[5]),pack2(h[6],h[7]));
            uint4 ul = make_uint4(pack2(l[0],l[1]),pack2(l[2],l[3]),pack2(l[4],l[5]),pack2(l[6],l[7]));
            *(uint4*)&xh_s[(p + 1) & 1][mr * XS2 + kq * 8] = uh;
            *(uint4*)&xl_s[(p + 1) & 1][mr * XS2 + kq * 8] = ul;
#pragma unroll
            for (int j = 0; j < 4; ++j) {
                bcur_h[j] = bnxt_h[j];   // renamed away by full unroll
                bcur_l[j] = bnxt_l[j];
            }
        }
    }

    // -------- Phase 2: +bias -> qk LDS (C/D layout: row(tok)=g*4+r, col=ln15) --------
    const int nrow = wv * 16 + ln15;  // proj output column 0..63
    {
        const float bias = (nrow < 32) ? bq[nrow] : bk[nrow - 32];
#pragma unroll
        for (int r = 0; r < 4; ++r)
            qk_f[(g * 4 + r) * QS + nrow] = acc[r] + bias;
    }
    __syncthreads();

    // -------- Phase 3: z = q+k (split), lnA = -0.5(|q|^2+|k|^2) --------
    if (tid < 128) {
        const int tok = tid >> 3, grp = tid & 7;
        float4 qv = *(const float4*)&qk_f[tok * QS + grp * 4];
        float4 kv = *(const float4*)&qk_f[tok * QS + 32 + grp * 4];
        float z0 = qv.x + kv.x, z1 = qv.y + kv.y, z2 = qv.z + kv.z, z3 = qv.w + kv.w;
        float p = qv.x*qv.x + qv.y*qv.y + qv.z*qv.z + qv.w*qv.w
                + kv.x*kv.x + kv.y*kv.y + kv.z*kv.z + kv.w*kv.w;
        short h0,h1,h2,h3, l0,l1,l2,l3;
        split_bf16(z0,h0,l0); split_bf16(z1,h1,l1);
        split_bf16(z2,h2,l2); split_bf16(z3,h3,l3);
        *(uint2*)&zh_s[tok * ZS + grp * 4] = make_uint2(pack2(h0,h1), pack2(h2,h3));
        *(uint2*)&zl_s[tok * ZS + grp * 4] = make_uint2(pack2(l0,l1), pack2(l2,l3));
        p += __shfl_xor(p, 1);
        p += __shfl_xor(p, 2);
        p += __shfl_xor(p, 4);
        if (grp == 0) lnA_f[tok] = -0.5f * p;
    }
    __syncthreads();

    // -------- Phase 4: S[16 tok][256] = z @ w^T (3-pass split); wave wv: features wv*64.. --------
    f32x4 facc[4];
#pragma unroll
    for (int i = 0; i < 4; ++i) facc[i] = (f32x4){0.f,0.f,0.f,0.f};

    bf16x8 a_h = *(const bf16x8*)&zh_s[ln15 * ZS + g * 8];
    bf16x8 a_l = *(const bf16x8*)&zl_s[ln15 * ZS + g * 8];
#pragma unroll
    for (int i = 0; i < 4; ++i) {
        const int nf = (wv * 4 + i) * 16 + ln15;    // feature 0..255
        bf16x8 bh = *(const bf16x8*)(ws + WF_H_OFF + (size_t)nf * DH + g * 8);
        bf16x8 bl = *(const bf16x8*)(ws + WF_L_OFF + (size_t)nf * DH + g * 8);
        facc[i] = __builtin_amdgcn_mfma_f32_16x16x32_bf16(a_h, bh, facc[i], 0, 0, 0);
        facc[i] = __builtin_amdgcn_mfma_f32_16x16x32_bf16(a_h, bl, facc[i], 0, 0, 0);
        facc[i] = __builtin_amdgcn_mfma_f32_16x16x32_bf16(a_l, bh, facc[i], 0, 0, 0);
    }

    // -------- Phase 5: R = 0.5*(exp(lnA+s)+exp(lnA-s)) --------
    float lnAv[4];
#pragma unroll
    for (int r = 0; r < 4; ++r) lnAv[r] = lnA_f[g * 4 + r];

#pragma unroll
    for (int i = 0; i < 4; ++i) {
        const int n = (wv * 4 + i) * 16 + ln15;
#pragma unroll
        for (int r = 0; r < 4; ++r) {
            float s = facc[i][r];
            float R = 0.5f * (__expf(lnAv[r] + s) + __expf(lnAv[r] - s));
            out[(t0 + g * 4 + r) * M_FEAT + n] = R;
        }
    }
}

extern "C" void kernel_launch(void* const* d_in, const int* in_sizes, int n_in,
                              void* d_out, int out_size, void* d_ws, size_t ws_size,
                              hipStream_t stream) {
    const float* x  = (const float*)d_in[0];
    const float* Wq = (const float*)d_in[1];
    const float* bq = (const float*)d_in[2];
    const float* Wk = (const float*)d_in[3];
    const float* bk = (const float*)d_in[4];
    // d_in[5], d_in[6] = Wv, bv: dead in the reference
    const float* w  = (const float*)d_in[7];
    float* out = (float*)d_out;
    short* ws  = (short*)d_ws;   // 288 KB used

    k_prep<<<dim3(17), dim3(256), 0, stream>>>(Wq, Wk, w, ws);
    k_main<<<dim3(BT / TB), dim3(256), 0, stream>>>(x, bq, bk, ws, out);
}

// Round 5
// 123.318 us; speedup vs baseline: 1.5563x; 1.0064x over previous
//
#include <hip/hip_runtime.h>
#include <cstdint>

#define E_DIM   1024
#define DH      32
#define M_FEAT  256
#define BT      16384

typedef __attribute__((ext_vector_type(8))) short bf16x8;
typedef __attribute__((ext_vector_type(4))) float f32x4;

// ws layout (shorts): proj W in MFMA-fragment order, flat = (nt*32 + sub)*512 + lane*8
#define WP_H_OFF 0
#define WP_L_OFF 65536

// ---- cheap 2-term bf16 split: h = trunc16(f), l = trunc16(f - h). ----
// residual |f-h-l| <= 2^-16 |f|; packing via v_perm_b32 (1 instr / 2 floats).
__device__ __forceinline__ unsigned perm_hi2(unsigned lo_src, unsigned hi_src) {
    // result = (hi16 of lo_src) | (hi16 of hi_src) << 16
#if __has_builtin(__builtin_amdgcn_perm)
    return __builtin_amdgcn_perm(hi_src, lo_src, 0x07060302u);
#else
    return (lo_src >> 16) | (hi_src & 0xFFFF0000u);
#endif
}

__device__ __forceinline__ void split2(float f0, float f1, unsigned& ph, unsigned& pl) {
    unsigned u0 = __builtin_bit_cast(unsigned, f0);
    unsigned u1 = __builtin_bit_cast(unsigned, f1);
    ph = perm_hi2(u0, u1);
    float d0 = f0 - __builtin_bit_cast(float, u0 & 0xFFFF0000u);
    float d1 = f1 - __builtin_bit_cast(float, u1 & 0xFFFF0000u);
    pl = perm_hi2(__builtin_bit_cast(unsigned, d0), __builtin_bit_cast(unsigned, d1));
}

__device__ __forceinline__ void split8(const float4& a, const float4& b,
                                       uint4& uh, uint4& ul) {
    split2(a.x, a.y, uh.x, ul.x);
    split2(a.z, a.w, uh.y, ul.y);
    split2(b.x, b.y, uh.z, ul.z);
    split2(b.z, b.w, uh.w, ul.w);
}

// ---------- prep: coalesced LDS-transpose split of [Wq|Wk] into fragment order ----------
__global__ __launch_bounds__(256) void k_prep(
    const float* __restrict__ Wq, const float* __restrict__ Wk,
    short* __restrict__ ws)
{
    __shared__ float wlds[128 * 36];   // [k 0..127][n 0..31], stride 36 floats
    const int b = blockIdx.x, tid = threadIdx.x;
    const float* __restrict__ src = (b < 8) ? Wq : Wk;
    const int k0 = (b & 7) * 128;
    const int nbase = (b < 8) ? 0 : 32;
#pragma unroll
    for (int it = 0; it < 4; ++it) {               // coalesced read 128x32 floats
        int f = it * 256 + tid;                    // float4 index
        int k = f >> 3, c4 = f & 7;
        float4 v = *(const float4*)(src + (size_t)(k0 + k) * DH + c4 * 4);
        *(float4*)&wlds[k * 36 + c4 * 4] = v;
    }
    __syncthreads();
    const int n = tid >> 3, kq = tid & 7;
    const int n_g = nbase + n;
    const int nt = n_g >> 4, ln = n_g & 15;
#pragma unroll
    for (int rep = 0; rep < 4; ++rep) {
        int kk = rep * 8 + kq;                     // k-quad within this 128-slab
        int k_g = k0 + kk * 4;
        float f0 = wlds[(kk * 4 + 0) * 36 + n];
        float f1 = wlds[(kk * 4 + 1) * 36 + n];
        float f2 = wlds[(kk * 4 + 2) * 36 + n];
        float f3 = wlds[(kk * 4 + 3) * 36 + n];
        uint2 ph, pl;
        split2(f0, f1, ph.x, pl.x);
        split2(f2, f3, ph.y, pl.y);
        int sub = k_g >> 5;                        // global 32-k subchunk 0..31
        int g = (k_g >> 3) & 3, j0 = k_g & 7;
        int lane = g * 16 + ln;
        size_t flat = ((size_t)(nt * 32 + sub)) * 512 + lane * 8 + j0;
        *(uint2*)(ws + WP_H_OFF + flat) = ph;
        *(uint2*)(ws + WP_L_OFF + flat) = pl;
    }
}

// ---------- fused main: 16 tok/block, BK=128 pairs, dbuf LDS + dbuf B-frag registers ----------
#define TB 16
#define XS2 136  // x LDS row stride in shorts (128 data + 8 pad) = 272 B
#define QS 68    // qk row stride in floats
#define ZS 40    // z row stride in shorts

__global__ __launch_bounds__(256, 4) void k_main(
    const float* __restrict__ x, const float* __restrict__ bq,
    const float* __restrict__ bk, const short* __restrict__ ws,
    const float* __restrict__ w, float* __restrict__ out)
{
    __shared__ __align__(16) short xh_s[2][TB * XS2];
    __shared__ __align__(16) short xl_s[2][TB * XS2];
    __shared__ __align__(16) float qk_f[TB * QS];
    __shared__ __align__(16) short zh_s[TB * ZS];
    __shared__ __align__(16) short zl_s[TB * ZS];
    __shared__ float lnA_f[TB];

    const int tid  = threadIdx.x;
    const int lane = tid & 63;
    const int wv   = __builtin_amdgcn_readfirstlane(tid >> 6);  // 0..3
    const int ln15 = lane & 15;
    const int g    = lane >> 4;                                  // 0..3
    const long t0  = (long)blockIdx.x * TB;

    const int nrow = wv * 16 + ln15;   // proj output column 0..63
    const float bias = (nrow < 32) ? bq[nrow] : bk[nrow - 32];   // preload early

    // -------- Phase 1: C[16 tok][64] = x @ [Wq|Wk] (3-pass split bf16 MFMA) --------
    const int kq = tid & 15;          // 8-k group 0..15 within 128-wide pair
    const int mr = tid >> 4;          // token row 0..15

    f32x4 acc = {0.f, 0.f, 0.f, 0.f};

    const short* wpB_h = ws + WP_H_OFF + (size_t)(wv * 32) * 512 + lane * 8;
    const short* wpB_l = ws + WP_L_OFF + (size_t)(wv * 32) * 512 + lane * 8;
    const float* xrow  = x + (t0 + mr) * E_DIM + kq * 8;

    // stage pair 0 + preload its B fragments
    float4 sa = *(const float4*)(xrow + 0);
    float4 sb = *(const float4*)(xrow + 4);
    bf16x8 bcur_h[4], bcur_l[4], bnxt_h[4], bnxt_l[4];
#pragma unroll
    for (int j = 0; j < 4; ++j) {
        bcur_h[j] = *(const bf16x8*)(wpB_h + (size_t)j * 512);
        bcur_l[j] = *(const bf16x8*)(wpB_l + (size_t)j * 512);
    }
    {
        uint4 uh, ul;
        split8(sa, sb, uh, ul);
        *(uint4*)&xh_s[0][mr * XS2 + kq * 8] = uh;
        *(uint4*)&xl_s[0][mr * XS2 + kq * 8] = ul;
    }

#pragma unroll
    for (int p = 0; p < 8; ++p) {
        __syncthreads();              // buf (p&1) fully staged; prior reads of it done
        if (p < 7) {                  // prefetch next pair: x + B frags (full pair-period window)
            sa = *(const float4*)(xrow + (p + 1) * 128);
            sb = *(const float4*)(xrow + (p + 1) * 128 + 4);
#pragma unroll
            for (int j = 0; j < 4; ++j) {
                bnxt_h[j] = *(const bf16x8*)(wpB_h + (size_t)((p + 1) * 4 + j) * 512);
                bnxt_l[j] = *(const bf16x8*)(wpB_l + (size_t)((p + 1) * 4 + j) * 512);
            }
        }
#pragma unroll
        for (int j = 0; j < 4; ++j) {
            bf16x8 ah = *(const bf16x8*)&xh_s[p & 1][ln15 * XS2 + j * 32 + g * 8];
            bf16x8 al = *(const bf16x8*)&xl_s[p & 1][ln15 * XS2 + j * 32 + g * 8];
            acc = __builtin_amdgcn_mfma_f32_16x16x32_bf16(ah, bcur_h[j], acc, 0, 0, 0);
            acc = __builtin_amdgcn_mfma_f32_16x16x32_bf16(ah, bcur_l[j], acc, 0, 0, 0);
            acc = __builtin_amdgcn_mfma_f32_16x16x32_bf16(al, bcur_h[j], acc, 0, 0, 0);
        }
        if (p < 7) {
            uint4 uh, ul;
            split8(sa, sb, uh, ul);
            *(uint4*)&xh_s[(p + 1) & 1][mr * XS2 + kq * 8] = uh;
            *(uint4*)&xl_s[(p + 1) & 1][mr * XS2 + kq * 8] = ul;
#pragma unroll
            for (int j = 0; j < 4; ++j) {
                bcur_h[j] = bnxt_h[j];   // renamed away by full unroll
                bcur_l[j] = bnxt_l[j];
            }
        }
    }

    // issue feature-w fp32 fragment loads now; 2 barrier phases cover their latency
    float4 wfa[4], wfb[4];
#pragma unroll
    for (int i = 0; i < 4; ++i) {
        const int nf = (wv * 4 + i) * 16 + ln15;    // feature 0..255
        wfa[i] = *(const float4*)(w + (size_t)nf * DH + g * 8);
        wfb[i] = *(const float4*)(w + (size_t)nf * DH + g * 8 + 4);
    }

    // -------- Phase 2: +bias -> qk LDS (C/D layout: row(tok)=g*4+r, col=ln15) --------
#pragma unroll
    for (int r = 0; r < 4; ++r)
        qk_f[(g * 4 + r) * QS + nrow] = acc[r] + bias;
    __syncthreads();

    // -------- Phase 3: z = q+k (split), lnA = -0.5(|q|^2+|k|^2) --------
    if (tid < 128) {
        const int tok = tid >> 3, grp = tid & 7;
        float4 qv = *(const float4*)&qk_f[tok * QS + grp * 4];
        float4 kv = *(const float4*)&qk_f[tok * QS + 32 + grp * 4];
        float z0 = qv.x + kv.x, z1 = qv.y + kv.y, z2 = qv.z + kv.z, z3 = qv.w + kv.w;
        float p = qv.x*qv.x + qv.y*qv.y + qv.z*qv.z + qv.w*qv.w
                + kv.x*kv.x + kv.y*kv.y + kv.z*kv.z + kv.w*kv.w;
        uint2 ph, pl;
        split2(z0, z1, ph.x, pl.x);
        split2(z2, z3, ph.y, pl.y);
        *(uint2*)&zh_s[tok * ZS + grp * 4] = ph;
        *(uint2*)&zl_s[tok * ZS + grp * 4] = pl;
        p += __shfl_xor(p, 1);
        p += __shfl_xor(p, 2);
        p += __shfl_xor(p, 4);
        if (grp == 0) lnA_f[tok] = -0.5f * p;
    }
    __syncthreads();

    // -------- Phase 4: S[16 tok][256] = z @ w^T (3-pass split); wave wv: features wv*64.. --------
    f32x4 facc[4];
#pragma unroll
    for (int i = 0; i < 4; ++i) facc[i] = (f32x4){0.f,0.f,0.f,0.f};

    bf16x8 a_h = *(const bf16x8*)&zh_s[ln15 * ZS + g * 8];
    bf16x8 a_l = *(const bf16x8*)&zl_s[ln15 * ZS + g * 8];
#pragma unroll
    for (int i = 0; i < 4; ++i) {
        uint4 uh, ul;
        split8(wfa[i], wfb[i], uh, ul);
        bf16x8 bh = __builtin_bit_cast(bf16x8, uh);
        bf16x8 bl = __builtin_bit_cast(bf16x8, ul);
        facc[i] = __builtin_amdgcn_mfma_f32_16x16x32_bf16(a_h, bh, facc[i], 0, 0, 0);
        facc[i] = __builtin_amdgcn_mfma_f32_16x16x32_bf16(a_h, bl, facc[i], 0, 0, 0);
        facc[i] = __builtin_amdgcn_mfma_f32_16x16x32_bf16(a_l, bh, facc[i], 0, 0, 0);
    }

    // -------- Phase 5: R = 0.5*(exp(lnA+s)+exp(lnA-s)) --------
    float lnAv[4];
#pragma unroll
    for (int r = 0; r < 4; ++r) lnAv[r] = lnA_f[g * 4 + r];

#pragma unroll
    for (int i = 0; i < 4; ++i) {
        const int n = (wv * 4 + i) * 16 + ln15;
#pragma unroll
        for (int r = 0; r < 4; ++r) {
            float s = facc[i][r];
            float R = 0.5f * (__expf(lnAv[r] + s) + __expf(lnAv[r] - s));
            out[(t0 + g * 4 + r) * M_FEAT + n] = R;
        }
    }
}

extern "C" void kernel_launch(void* const* d_in, const int* in_sizes, int n_in,
                              void* d_out, int out_size, void* d_ws, size_t ws_size,
                              hipStream_t stream) {
    const float* x  = (const float*)d_in[0];
    const float* Wq = (const float*)d_in[1];
    const float* bq = (const float*)d_in[2];
    const float* Wk = (const float*)d_in[3];
    const float* bk = (const float*)d_in[4];
    // d_in[5], d_in[6] = Wv, bv: dead in the reference
    const float* w  = (const float*)d_in[7];
    float* out = (float*)d_out;
    short* ws  = (short*)d_ws;   // 256 KB used

    k_prep<<<dim3(16), dim3(256), 0, stream>>>(Wq, Wk, ws);
    k_main<<<dim3(BT / TB), dim3(256), 0, stream>>>(x, bq, bk, ws, w, out);
}